// Round 21
// baseline (62.790 us; speedup 1.0000x reference)
//
#include <hip/hip_runtime.h>
#include <math.h>

#define N_ROIS 1024
#define C_DIM  1024

typedef __attribute__((ext_vector_type(8))) short short8;
typedef __attribute__((ext_vector_type(4))) float f32x4;

__device__ __forceinline__ unsigned short f2bf(float x) {
    union { float f; unsigned u; } v; v.f = x;
    unsigned r = v.u + 0x7fffu + ((v.u >> 16) & 1u);
    return (unsigned short)(r >> 16);
}
__device__ __forceinline__ float bf2f(unsigned short u) {
    return __uint_as_float((unsigned)u << 16);
}
// HW packed f32x2 -> bf16x2 (RNE), single VALU op on gfx950
__device__ __forceinline__ unsigned cvtpk(float lo, float hi) {
    unsigned r;
    asm("v_cvt_pk_bf16_f32 %0, %1, %2" : "=v"(r) : "v"(lo), "v"(hi));
    return r;
}
// sin(2*pi*rev) with |rev| large: fract then HW v_sin
__device__ __forceinline__ float sin_rev(float rev) {
    return __builtin_amdgcn_sinf(__builtin_amdgcn_fractf(rev));
}

// ---------------------------------------------------------------------------
// Bulk f32 -> bf16 convert of 4 tensors (1M elems each).
// ---------------------------------------------------------------------------
__global__ __launch_bounds__(256) void cvt_kernel(
    const float* __restrict__ s0, const float* __restrict__ s1,
    const float* __restrict__ s2, const float* __restrict__ s3,
    unsigned short* __restrict__ d0, unsigned short* __restrict__ d1,
    unsigned short* __restrict__ d2, unsigned short* __restrict__ d3)
{
    const float* s; unsigned short* d;
    switch (blockIdx.y) {
        case 0:  s = s0; d = d0; break;
        case 1:  s = s1; d = d1; break;
        case 2:  s = s2; d = d2; break;
        default: s = s3; d = d3; break;
    }
    const int i = (blockIdx.x * 256 + threadIdx.x) * 8;
    float4 a = *(const float4*)&s[i];
    float4 b = *(const float4*)&s[i + 4];
    uint4 o;
    o.x = cvtpk(a.x, a.y); o.y = cvtpk(a.z, a.w);
    o.z = cvtpk(b.x, b.y); o.w = cvtpk(b.z, b.w);
    *(uint4*)&d[i] = o;
}

struct Triples {
    const unsigned short* A[3];
    const unsigned short* B[3];
    unsigned short*       C[3];
    const float*          bias[3];
};

// ---------------------------------------------------------------------------
// prep_kernel: 1408 blocks = 176 x 8 XCDs (bx&7 = XCD, nwg%8==0 so the
// round-robin mapping is exact). XCD-AWARE placement: XCD pair (2z, 2z+1)
// hosts gemm z (64 blocks each half) so each XCD's L2 working set is
// feats (2MB) + ONE weight (2MB) = 4MB = L2 size (was 8MB mixed -> thrash).
// Remaining slots on XCD 0-5 (112 each) + all of XCD 6,7 (176 each) = 1024
// pos blocks. GEMM path (64x128, BK=32): GLD double-buffered, __syncthreads.
// pos path: small-LDS shared-mbox; sin via fma+fract+v_sin.
// ---------------------------------------------------------------------------
__global__ __launch_bounds__(256) void prep_kernel(
    Triples tr, const float* __restrict__ rois, const float* __restrict__ Wg,
    const float* __restrict__ bg, unsigned short* __restrict__ logw)
{
    __shared__ __align__(16) char smem[24576];
    const int bx = blockIdx.x;
    const int t  = threadIdx.x;
    const int xcd  = bx & 7;          // XCD id (1408 % 8 == 0 -> exact)
    const int slot = bx >> 3;         // 0..175 within XCD

    if (xcd < 6 && slot < 64) {
        // ================= GEMM path =================
        const int z  = xcd >> 1;                           // 0..2
        const int r3 = (xcd & 1) * 64 + slot;              // 0..127
        const int m0 = (r3 >> 3) * 64, n0 = (r3 & 7) * 128;
        const unsigned short* A = tr.A[z];
        const unsigned short* B = tr.B[z];

        const int lane = t & 63, w = t >> 6;
        const int lx = lane & 15, qw = lane >> 4;

#define PGLD(srcp, dstoff) __builtin_amdgcn_global_load_lds( \
        (const __attribute__((address_space(1))) void*)(srcp), \
        (__attribute__((address_space(3))) void*)(smem + (dstoff)), 16, 0, 0)

        const int rsub = lane >> 2;                        // 0..15
        const int sg   = ((lane & 3) ^ (rsub & 3)) * 8;    // swizzled k-chunk
#define STAGE(bb, kk) do { \
        PGLD(A + (size_t)(m0 + w * 16 + rsub) * 1024 + (kk) + sg, \
             (bb) * 4096 + w * 1024 + lane * 16); \
        PGLD(B + (size_t)(n0 + w * 32 + rsub) * 1024 + (kk) + sg, \
             8192 + (bb) * 8192 + (w * 2) * 1024 + lane * 16); \
        PGLD(B + (size_t)(n0 + w * 32 + 16 + rsub) * 1024 + (kk) + sg, \
             8192 + (bb) * 8192 + (w * 2 + 1) * 1024 + lane * 16); \
    } while (0)

        f32x4 acc[2][4];
        const f32x4 z4 = {0.f, 0.f, 0.f, 0.f};
#pragma unroll
        for (int i = 0; i < 2; ++i)
#pragma unroll
            for (int j = 0; j < 4; ++j) acc[i][j] = z4;

        const int wm = (w & 1) * 32, wn = (w >> 1) * 64;
        const int rdsw = (qw ^ (lx & 3)) << 4;             // read-side XOR slot

        STAGE(0, 0);
        __syncthreads();

        for (int k0 = 0; k0 < 1024; k0 += 32) {
            const int cur = (k0 >> 5) & 1;
            if (k0 + 32 < 1024) STAGE(cur ^ 1, k0 + 32);
            const char* Ac = smem + cur * 4096;
            const char* Bc = smem + 8192 + cur * 8192;
            short8 af[2], bfr[4];
#pragma unroll
            for (int mi = 0; mi < 2; ++mi)
                af[mi] = *(const short8*)(Ac + (wm + mi * 16 + lx) * 64 + rdsw);
#pragma unroll
            for (int ni = 0; ni < 4; ++ni)
                bfr[ni] = *(const short8*)(Bc + (wn + ni * 16 + lx) * 64 + rdsw);
#pragma unroll
            for (int mi = 0; mi < 2; ++mi)
#pragma unroll
                for (int ni = 0; ni < 4; ++ni)
                    acc[mi][ni] = __builtin_amdgcn_mfma_f32_16x16x32_bf16(
                        af[mi], bfr[ni], acc[mi][ni], 0, 0, 0);
            __syncthreads();   // drains GLDs for next buffer; cur reads done
        }
#undef STAGE
#undef PGLD

        const float* bias = tr.bias[z];
        unsigned short* C = tr.C[z];
        const float sc = (z == 0) ? 0.125f : 1.0f;   // fold softmax scale into q
        const int r0 = qw * 4, cc = lx;
#pragma unroll
        for (int mi = 0; mi < 2; ++mi)
#pragma unroll
            for (int ni = 0; ni < 4; ++ni) {
                const int col = n0 + wn + ni * 16 + cc;
                const float bb = bias ? bias[col] : 0.f;
                const int rowi = m0 + wm + mi * 16 + r0;
                const unsigned p01 = cvtpk((acc[mi][ni][0] + bb) * sc,
                                           (acc[mi][ni][1] + bb) * sc);
                const unsigned p23 = cvtpk((acc[mi][ni][2] + bb) * sc,
                                           (acc[mi][ni][3] + bb) * sc);
                C[(size_t)rowi * 1024 + col]       = (unsigned short)(p01 & 0xffff);
                C[(size_t)(rowi + 1) * 1024 + col] = (unsigned short)(p01 >> 16);
                C[(size_t)(rowi + 2) * 1024 + col] = (unsigned short)(p23 & 0xffff);
                C[(size_t)(rowi + 3) * 1024 + col] = (unsigned short)(p23 >> 16);
            }
    } else {
        // ================= pos path (small-LDS, shared mbox) =================
        unsigned short* wg_s = (unsigned short*)smem;            // 2304 B
        float* bg_s = (float*)(smem + 2304);                     // 64 B
        float (*mbox)[4] = (float(*)[4])(smem + 2368);           // 4 KB
        unsigned short* ptile0 = (unsigned short*)(smem + 6464); // 4 x 4480 B
        // pos id: XCD<6 -> 112 slots (64..175); XCD 6,7 -> 176 slots.
        const int pb = (xcd < 6) ? (xcd * 112 + (slot - 64))
                                 : (672 + (xcd - 6) * 176 + slot);  // 0..1023
        const int ngrp = pb >> 2;
        const int mc   = (pb & 3) * 256;
        const int lane = t & 63, w = t >> 6;
        const int g = lane & 15, qw = lane >> 4;
        unsigned short* pt = ptile0 + w * 2240;

        if (t < 128) {
            const int gi = t >> 3, c = (t & 7) * 8;
            unsigned short* d = &wg_s[gi * 72 + c];
#pragma unroll
            for (int u2 = 0; u2 < 8; ++u2) d[u2] = f2bf(Wg[gi * 64 + c + u2]);
        }
        if (t < 16) bg_s[t] = bg[t];
        {
            const int m = mc + t;
            const float x1 = rois[m * 5 + 1], y1 = rois[m * 5 + 2];
            const float x2 = rois[m * 5 + 3], y2 = rois[m * 5 + 4];
            mbox[t][0] = (x1 + x2) * 0.5f;
            mbox[t][1] = (y1 + y2) * 0.5f;
            mbox[t][2] = __logf(x2 - x1 + 1.f);
            mbox[t][3] = __logf(y2 - y1 + 1.f);
        }
        const int n = ngrp * 4 + w;
        const float x1 = rois[n * 5 + 1], y1 = rois[n * 5 + 2];
        const float x2 = rois[n * 5 + 3], y2 = rois[n * 5 + 4];
        const float cxn = (x1 + x2) * 0.5f, cyn = (y1 + y2) * 0.5f;
        const float wn = x2 - x1 + 1.f, hn = y2 - y1 + 1.f;
        const float iwn = 1.f / wn, ihn = 1.f / hn;
        const float lwn = __logf(wn), lhn = __logf(hn);
        __syncthreads();

        const float cr = (qw & 1) ? 0.25f : 0.f;
        const int f0 = qw >> 1;
        const short8 bf0 = *(const short8*)&wg_s[g * 72 + qw * 8];
        const short8 bf1 = *(const short8*)&wg_s[g * 72 + qw * 8 + 32];
        const float bgv = bg_s[g];
        const float revd[8] = {15.91549431f, 6.7115081f, 2.8302193f, 1.1934936f,
                               0.5032921f, 0.2122365f, 0.0894993f, 0.0377415f};

        for (int cl = 0; cl < 16; ++cl) {
            float4 mb = *(const float4*)&mbox[cl * 16 + g][0];   // cx, cy, lw, lh
            const float p0 = (f0 == 0)
                     ? __logf(fmaxf(fabsf((cxn - mb.x) * iwn), 1e-3f))
                     : __logf(fmaxf(fabsf((cyn - mb.y) * ihn), 1e-3f));
            const float p1 = (f0 == 0) ? (lwn - mb.z) : (lhn - mb.w);
            float s0v[8], s1v[8];
#pragma unroll
            for (int rr = 0; rr < 8; ++rr) {
                const float rv = revd[rr];
                s0v[rr] = sin_rev(fmaf(p0, rv, cr));
                s1v[rr] = sin_rev(fmaf(p1, rv, cr));
            }
            union { uint4 u; short8 s; } a0, a1;
            a0.u.x = cvtpk(s0v[0], s0v[1]); a0.u.y = cvtpk(s0v[2], s0v[3]);
            a0.u.z = cvtpk(s0v[4], s0v[5]); a0.u.w = cvtpk(s0v[6], s0v[7]);
            a1.u.x = cvtpk(s1v[0], s1v[1]); a1.u.y = cvtpk(s1v[2], s1v[3]);
            a1.u.z = cvtpk(s1v[4], s1v[5]); a1.u.w = cvtpk(s1v[6], s1v[7]);
            f32x4 acc = {0.f, 0.f, 0.f, 0.f};
            acc = __builtin_amdgcn_mfma_f32_16x16x32_bf16(a0.s, bf0, acc, 0, 0, 0);
            acc = __builtin_amdgcn_mfma_f32_16x16x32_bf16(a1.s, bf1, acc, 0, 0, 0);
            const float l0 = __logf(fmaxf(acc[0] + bgv, 1e-6f));
            const float l1 = __logf(fmaxf(acc[1] + bgv, 1e-6f));
            const float l2 = __logf(fmaxf(acc[2] + bgv, 1e-6f));
            const float l3 = __logf(fmaxf(acc[3] + bgv, 1e-6f));
            uint2 pk;
            pk.x = cvtpk(l0, l1);
            pk.y = cvtpk(l2, l3);
            *(uint2*)&pt[g * 140 + (cl & 7) * 16 + qw * 4] = pk;

            if ((cl & 7) == 7) {
                const int fl = cl >> 3;
                const int gg = lane >> 2, c4 = lane & 3;
                unsigned short* op = logw + (size_t)n * 16384 + gg * 1024 + mc + fl * 128;
                const unsigned short* rp = &pt[gg * 140];
#pragma unroll
                for (int j = 0; j < 8; ++j) {
                    const int mo = (c4 + j * 4) * 4;
                    *(uint2*)&op[mo] = *(const uint2*)&rp[mo];
                }
            }
        }
    }
}

// ---------------------------------------------------------------------------
// attn: r13/r18 version (flash, DMA-staged K/FW/logw double-buffered LDS,
// 4 waves, __syncthreads per chunk) — known-good.
// ---------------------------------------------------------------------------
#define QOFF 0
#define KOFF 8192
#define FOFF 24576
#define LOFF 40960
#define POFF 57344
#define PPAD 72

__global__ __launch_bounds__(256) void attn_kernel(
    const unsigned short* __restrict__ qb, const unsigned short* __restrict__ kb,
    const unsigned short* __restrict__ logw, const unsigned short* __restrict__ FWt,
    const float* __restrict__ bv, float* __restrict__ out)
{
    __shared__ __align__(16) char smem[66560];

    const int t = threadIdx.x;
    const int bid = blockIdx.x;
    const int g  = (bid & 7) * 2 + ((bid >> 3) >> 4);
    const int n0 = ((bid >> 3) & 15) * 64;

    const int lane = t & 63, W = t >> 6;
    const int qw = lane >> 4, lx = lane & 15;
    const int lx7 = lx & 7;
    const int r8 = lane >> 3, u = lane & 7;

#define GLD(srcp, ldsoff) __builtin_amdgcn_global_load_lds( \
        (const __attribute__((address_space(1))) void*)(srcp), \
        (__attribute__((address_space(3))) void*)(smem + (ldsoff)), 16, 0, 0)

#pragma unroll
    for (int j = 0; j < 2; ++j) {
        const int c = W * 2 + j;
        const int r = c * 8 + r8;
        GLD(qb + (size_t)(n0 + r) * 1024 + g * 64 + ((u ^ (r & 7)) * 8),
            QOFF + c * 1024);
        GLD(kb + (size_t)r * 1024 + g * 64 + ((u ^ (r & 7)) * 8),
            KOFF + c * 1024);
        GLD(FWt + (size_t)(g * 64 + r) * 1024 + ((u ^ (r & 7)) * 8),
            FOFF + c * 1024);
        GLD(logw + (size_t)(n0 + r) * 16384 + g * 1024 + (((2 * u) ^ (r & 6)) * 4),
            LOFF + c * 1024);
    }
    __syncthreads();

    const unsigned short* qS = (const unsigned short*)(smem + QOFF);
    const int qrow = W * 16 + lx;
    const short8 bq0 = *(const short8*)(qS + qrow * 64 + ((qw ^ lx7) * 8));
    const short8 bq1 = *(const short8*)(qS + qrow * 64 + (((qw + 4) ^ lx7) * 8));
    unsigned short* Pw = (unsigned short*)(smem + POFF) + W * 16 * PPAD;

    f32x4 acc[4];
    const f32x4 z4 = {0.f, 0.f, 0.f, 0.f};
#pragma unroll
    for (int nb = 0; nb < 4; ++nb) acc[nb] = z4;
    float mrow = -1e30f, srow = 0.f;

    for (int i = 0; i < 16; ++i) {
        const int cur = i & 1;
        if (i < 15) {
            const int mc = (i + 1) * 64;
            const int nxt = cur ^ 1;
#pragma unroll
            for (int j = 0; j < 2; ++j) {
                const int c = W * 2 + j;
                const int r = c * 8 + r8;
                GLD(kb + (size_t)(mc + r) * 1024 + g * 64 + ((u ^ (r & 7)) * 8),
                    KOFF + nxt * 8192 + c * 1024);
                GLD(FWt + (size_t)(g * 64 + r) * 1024 + mc + ((u ^ (r & 7)) * 8),
                    FOFF + nxt * 8192 + c * 1024);
                GLD(logw + (size_t)(n0 + r) * 16384 + g * 1024 + mc
                        + (((2 * u) ^ (r & 6)) * 4),
                    LOFF + nxt * 8192 + c * 1024);
            }
        }

        const unsigned short* Kc = (const unsigned short*)(smem + KOFF + cur * 8192);
        const unsigned short* Fc = (const unsigned short*)(smem + FOFF + cur * 8192);
        const unsigned short* Lc = (const unsigned short*)(smem + LOFF + cur * 8192);

        f32x4 s[4];
#pragma unroll
        for (int tt = 0; tt < 4; ++tt) {
            const unsigned short* kr = Kc + (tt * 16 + lx) * 64;
            short8 a0 = *(const short8*)(kr + ((qw ^ lx7) * 8));
            short8 a1 = *(const short8*)(kr + (((qw + 4) ^ lx7) * 8));
            f32x4 z = z4;
            z = __builtin_amdgcn_mfma_f32_16x16x32_bf16(a0, bq0, z, 0, 0, 0);
            s[tt] = __builtin_amdgcn_mfma_f32_16x16x32_bf16(a1, bq1, z, 0, 0, 0);
        }

        const unsigned short* Lr = Lc + (W * 16 + lx) * 64;
        float v[4][4];
        float cmx = -1e30f;
#pragma unroll
        for (int tt = 0; tt < 4; ++tt) {
            const int off = ((tt * 32 + qw * 8) ^ ((lx & 6) << 3)) >> 1;
            const uint2 lw = *(const uint2*)(Lr + off);
            v[tt][0] = s[tt][0] + bf2f((unsigned short)(lw.x & 0xffff));
            v[tt][1] = s[tt][1] + bf2f((unsigned short)(lw.x >> 16));
            v[tt][2] = s[tt][2] + bf2f((unsigned short)(lw.y & 0xffff));
            v[tt][3] = s[tt][3] + bf2f((unsigned short)(lw.y >> 16));
            cmx = fmaxf(cmx, fmaxf(fmaxf(v[tt][0], v[tt][1]), fmaxf(v[tt][2], v[tt][3])));
        }
        cmx = fmaxf(cmx, __shfl_xor(cmx, 16));
        cmx = fmaxf(cmx, __shfl_xor(cmx, 32));

        const float nm = fmaxf(mrow, cmx);
        const float f  = __expf(mrow - nm);
        mrow = nm;
        srow *= f;
#pragma unroll
        for (int nb = 0; nb < 4; ++nb) {
            acc[nb][0] *= f; acc[nb][1] *= f;
            acc[nb][2] *= f; acc[nb][3] *= f;
        }

#pragma unroll
        for (int tt = 0; tt < 4; ++tt) {
            const float p0 = __expf(v[tt][0] - nm);
            const float p1 = __expf(v[tt][1] - nm);
            const float p2 = __expf(v[tt][2] - nm);
            const float p3 = __expf(v[tt][3] - nm);
            srow += (p0 + p1) + (p2 + p3);
            uint2 pk;
            pk.x = cvtpk(p0, p1);
            pk.y = cvtpk(p2, p3);
            *(uint2*)&Pw[lx * PPAD + tt * 16 + qw * 4] = pk;
        }

#pragma unroll
        for (int ks = 0; ks < 2; ++ks) {
            const short8 ap = *(const short8*)&Pw[lx * PPAD + ks * 32 + qw * 8];
#pragma unroll
            for (int nb = 0; nb < 4; ++nb) {
                const unsigned short* fr = Fc + (nb * 16 + lx) * 64;
                short8 fb = *(const short8*)(fr + (((ks * 4 + qw) ^ lx7) * 8));
                acc[nb] = __builtin_amdgcn_mfma_f32_16x16x32_bf16(fb, ap, acc[nb], 0, 0, 0);
            }
        }

        __syncthreads();   // drains DMA for i+1; all waves done with cur
    }

    srow += __shfl_xor(srow, 16);
    srow += __shfl_xor(srow, 32);
    const float inv = 1.f / srow;
    float* Ow = (float*)smem + W * 16 * 68;
#pragma unroll
    for (int nb = 0; nb < 4; ++nb)
#pragma unroll
        for (int r = 0; r < 4; ++r)
            Ow[lx * 68 + nb * 16 + qw * 4 + r] = acc[nb][r] * inv;
    {
        const int row = lane >> 2, d0 = (lane & 3) * 16;
        const float* Orow = (float*)smem + W * 16 * 68 + row * 68;
        float* op = out + (size_t)(n0 + W * 16 + row) * 1024 + g * 64 + d0;
#pragma unroll
        for (int j = 0; j < 4; ++j) {
            float4 o = *(const float4*)(Orow + d0 + j * 4);
            const float4 b4 = *(const float4*)&bv[g * 64 + d0 + j * 4];
            o.x += b4.x; o.y += b4.y; o.z += b4.z; o.w += b4.w;
            *(float4*)(op + j * 4) = o;
        }
    }
#undef GLD
}

extern "C" void kernel_launch(void* const* d_in, const int* in_sizes, int n_in,
                              void* d_out, int out_size, void* d_ws, size_t ws_size,
                              hipStream_t stream)
{
    const float* feats = (const float*)d_in[0];
    const float* rois  = (const float*)d_in[1];
    const float* Wq    = (const float*)d_in[2];
    const float* bq    = (const float*)d_in[3];
    const float* Wk    = (const float*)d_in[4];
    const float* bk    = (const float*)d_in[5];
    const float* Wg    = (const float*)d_in[6];
    const float* bg    = (const float*)d_in[7];
    const float* Wv    = (const float*)d_in[8];
    const float* bv    = (const float*)d_in[9];
    float* out = (float*)d_out;

    char* wsb = (char*)d_ws;
    unsigned short* logwb  = (unsigned short*)(wsb + (0ull  << 20));  // 32MB
    unsigned short* featsb = (unsigned short*)(wsb + (64ull << 20));
    unsigned short* qb     = (unsigned short*)(wsb + (66ull << 20));
    unsigned short* kb     = (unsigned short*)(wsb + (68ull << 20));
    unsigned short* FWtb   = (unsigned short*)(wsb + (70ull << 20));
    unsigned short* Wqb    = (unsigned short*)(wsb + (80ull << 20));  // away from logw
    unsigned short* Wkb    = (unsigned short*)(wsb + (82ull << 20));
    unsigned short* Wvb    = (unsigned short*)(wsb + (84ull << 20));

    cvt_kernel<<<dim3(512, 4), 256, 0, stream>>>(feats, Wq, Wk, Wv,
                                                 featsb, Wqb, Wkb, Wvb);

    Triples tr;
    tr.A[0] = featsb; tr.B[0] = Wqb;    tr.C[0] = qb;   tr.bias[0] = bq;
    tr.A[1] = featsb; tr.B[1] = Wkb;    tr.C[1] = kb;   tr.bias[1] = bk;
    tr.A[2] = Wvb;    tr.B[2] = featsb; tr.C[2] = FWtb; tr.bias[2] = nullptr;
    // 1408 blocks, XCD-clustered: gemm z on XCD pair (2z,2z+1), pos fills rest
    prep_kernel<<<1408, 256, 0, stream>>>(tr, rois, Wg, bg, logwb);

    attn_kernel<<<256, 256, 0, stream>>>(qb, kb, logwb, FWtb, bv, out);
}

// Round 22
// 60.208 us; speedup vs baseline: 1.0429x; 1.0429x over previous
//
#include <hip/hip_runtime.h>
#include <math.h>

#define N_ROIS 1024
#define C_DIM  1024

typedef __attribute__((ext_vector_type(8))) short short8;
typedef __attribute__((ext_vector_type(4))) float f32x4;

__device__ __forceinline__ unsigned short f2bf(float x) {
    union { float f; unsigned u; } v; v.f = x;
    unsigned r = v.u + 0x7fffu + ((v.u >> 16) & 1u);
    return (unsigned short)(r >> 16);
}
__device__ __forceinline__ float bf2f(unsigned short u) {
    return __uint_as_float((unsigned)u << 16);
}
// HW packed f32x2 -> bf16x2 (RNE), single VALU op on gfx950
__device__ __forceinline__ unsigned cvtpk(float lo, float hi) {
    unsigned r;
    asm("v_cvt_pk_bf16_f32 %0, %1, %2" : "=v"(r) : "v"(lo), "v"(hi));
    return r;
}
// sin(2*pi*rev) with |rev| large: fract then HW v_sin
__device__ __forceinline__ float sin_rev(float rev) {
    return __builtin_amdgcn_sinf(__builtin_amdgcn_fractf(rev));
}

// ---------------------------------------------------------------------------
// Bulk f32 -> bf16 convert of 4 tensors (1M elems each).
// ---------------------------------------------------------------------------
__global__ __launch_bounds__(256) void cvt_kernel(
    const float* __restrict__ s0, const float* __restrict__ s1,
    const float* __restrict__ s2, const float* __restrict__ s3,
    unsigned short* __restrict__ d0, unsigned short* __restrict__ d1,
    unsigned short* __restrict__ d2, unsigned short* __restrict__ d3)
{
    const float* s; unsigned short* d;
    switch (blockIdx.y) {
        case 0:  s = s0; d = d0; break;
        case 1:  s = s1; d = d1; break;
        case 2:  s = s2; d = d2; break;
        default: s = s3; d = d3; break;
    }
    const int i = (blockIdx.x * 256 + threadIdx.x) * 8;
    float4 a = *(const float4*)&s[i];
    float4 b = *(const float4*)&s[i + 4];
    uint4 o;
    o.x = cvtpk(a.x, a.y); o.y = cvtpk(a.z, a.w);
    o.z = cvtpk(b.x, b.y); o.w = cvtpk(b.z, b.w);
    *(uint4*)&d[i] = o;
}

struct Triples {
    const unsigned short* A[3];
    const unsigned short* B[3];
    unsigned short*       C[3];
    const float*          bias[3];
};

// ---------------------------------------------------------------------------
// prep_kernel: 1408 blocks = 128 groups x (3 gemm + 8 pos).
// GEMM path (64x128, BK=32): GLD double-buffered, __syncthreads.
// pos path: small-LDS shared-mbox; sin via fma+fract+v_sin.
// ---------------------------------------------------------------------------
__global__ __launch_bounds__(256) void prep_kernel(
    Triples tr, const float* __restrict__ rois, const float* __restrict__ Wg,
    const float* __restrict__ bg, unsigned short* __restrict__ logw)
{
    __shared__ __align__(16) char smem[24576];
    const int bx = blockIdx.x;
    const int t  = threadIdx.x;
    const int grp = bx / 11, rem = bx % 11;

    if (rem < 3) {
        // ================= GEMM path =================
        const int gid = grp * 3 + rem;                     // 0..383
        const int z   = gid >> 7;                          // 0..2
        const int r3  = gid & 127;
        const int m0 = (r3 >> 3) * 64, n0 = (r3 & 7) * 128;
        const unsigned short* A = tr.A[z];
        const unsigned short* B = tr.B[z];

        const int lane = t & 63, w = t >> 6;
        const int lx = lane & 15, qw = lane >> 4;

#define PGLD(srcp, dstoff) __builtin_amdgcn_global_load_lds( \
        (const __attribute__((address_space(1))) void*)(srcp), \
        (__attribute__((address_space(3))) void*)(smem + (dstoff)), 16, 0, 0)

        const int rsub = lane >> 2;                        // 0..15
        const int sg   = ((lane & 3) ^ (rsub & 3)) * 8;    // swizzled k-chunk
#define STAGE(bb, kk) do { \
        PGLD(A + (size_t)(m0 + w * 16 + rsub) * 1024 + (kk) + sg, \
             (bb) * 4096 + w * 1024 + lane * 16); \
        PGLD(B + (size_t)(n0 + w * 32 + rsub) * 1024 + (kk) + sg, \
             8192 + (bb) * 8192 + (w * 2) * 1024 + lane * 16); \
        PGLD(B + (size_t)(n0 + w * 32 + 16 + rsub) * 1024 + (kk) + sg, \
             8192 + (bb) * 8192 + (w * 2 + 1) * 1024 + lane * 16); \
    } while (0)

        f32x4 acc[2][4];
        const f32x4 z4 = {0.f, 0.f, 0.f, 0.f};
#pragma unroll
        for (int i = 0; i < 2; ++i)
#pragma unroll
            for (int j = 0; j < 4; ++j) acc[i][j] = z4;

        const int wm = (w & 1) * 32, wn = (w >> 1) * 64;
        const int rdsw = (qw ^ (lx & 3)) << 4;             // read-side XOR slot

        STAGE(0, 0);
        __syncthreads();

        for (int k0 = 0; k0 < 1024; k0 += 32) {
            const int cur = (k0 >> 5) & 1;
            if (k0 + 32 < 1024) STAGE(cur ^ 1, k0 + 32);
            const char* Ac = smem + cur * 4096;
            const char* Bc = smem + 8192 + cur * 8192;
            short8 af[2], bfr[4];
#pragma unroll
            for (int mi = 0; mi < 2; ++mi)
                af[mi] = *(const short8*)(Ac + (wm + mi * 16 + lx) * 64 + rdsw);
#pragma unroll
            for (int ni = 0; ni < 4; ++ni)
                bfr[ni] = *(const short8*)(Bc + (wn + ni * 16 + lx) * 64 + rdsw);
#pragma unroll
            for (int mi = 0; mi < 2; ++mi)
#pragma unroll
                for (int ni = 0; ni < 4; ++ni)
                    acc[mi][ni] = __builtin_amdgcn_mfma_f32_16x16x32_bf16(
                        af[mi], bfr[ni], acc[mi][ni], 0, 0, 0);
            __syncthreads();   // drains GLDs for next buffer; cur reads done
        }
#undef STAGE
#undef PGLD

        const float* bias = tr.bias[z];
        unsigned short* C = tr.C[z];
        const float sc = (z == 0) ? 0.125f : 1.0f;   // fold softmax scale into q
        const int r0 = qw * 4, cc = lx;
#pragma unroll
        for (int mi = 0; mi < 2; ++mi)
#pragma unroll
            for (int ni = 0; ni < 4; ++ni) {
                const int col = n0 + wn + ni * 16 + cc;
                const float bb = bias ? bias[col] : 0.f;
                const int rowi = m0 + wm + mi * 16 + r0;
                const unsigned p01 = cvtpk((acc[mi][ni][0] + bb) * sc,
                                           (acc[mi][ni][1] + bb) * sc);
                const unsigned p23 = cvtpk((acc[mi][ni][2] + bb) * sc,
                                           (acc[mi][ni][3] + bb) * sc);
                C[(size_t)rowi * 1024 + col]       = (unsigned short)(p01 & 0xffff);
                C[(size_t)(rowi + 1) * 1024 + col] = (unsigned short)(p01 >> 16);
                C[(size_t)(rowi + 2) * 1024 + col] = (unsigned short)(p23 & 0xffff);
                C[(size_t)(rowi + 3) * 1024 + col] = (unsigned short)(p23 >> 16);
            }
    } else {
        // ================= pos path (small-LDS, shared mbox) =================
        unsigned short* wg_s = (unsigned short*)smem;            // 2304 B
        float* bg_s = (float*)(smem + 2304);                     // 64 B
        float (*mbox)[4] = (float(*)[4])(smem + 2368);           // 4 KB
        unsigned short* ptile0 = (unsigned short*)(smem + 6464); // 4 x 4480 B
        const int pb = grp * 8 + (rem - 3);                      // 0..1023
        const int ngrp = pb >> 2;
        const int mc   = (pb & 3) * 256;
        const int lane = t & 63, w = t >> 6;
        const int g = lane & 15, qw = lane >> 4;
        unsigned short* pt = ptile0 + w * 2240;

        if (t < 128) {
            const int gi = t >> 3, c = (t & 7) * 8;
            unsigned short* d = &wg_s[gi * 72 + c];
#pragma unroll
            for (int u2 = 0; u2 < 8; ++u2) d[u2] = f2bf(Wg[gi * 64 + c + u2]);
        }
        if (t < 16) bg_s[t] = bg[t];
        {
            const int m = mc + t;
            const float x1 = rois[m * 5 + 1], y1 = rois[m * 5 + 2];
            const float x2 = rois[m * 5 + 3], y2 = rois[m * 5 + 4];
            mbox[t][0] = (x1 + x2) * 0.5f;
            mbox[t][1] = (y1 + y2) * 0.5f;
            mbox[t][2] = __logf(x2 - x1 + 1.f);
            mbox[t][3] = __logf(y2 - y1 + 1.f);
        }
        const int n = ngrp * 4 + w;
        const float x1 = rois[n * 5 + 1], y1 = rois[n * 5 + 2];
        const float x2 = rois[n * 5 + 3], y2 = rois[n * 5 + 4];
        const float cxn = (x1 + x2) * 0.5f, cyn = (y1 + y2) * 0.5f;
        const float wn = x2 - x1 + 1.f, hn = y2 - y1 + 1.f;
        const float iwn = 1.f / wn, ihn = 1.f / hn;
        const float lwn = __logf(wn), lhn = __logf(hn);
        __syncthreads();

        const float cr = (qw & 1) ? 0.25f : 0.f;
        const int f0 = qw >> 1;
        const short8 bf0 = *(const short8*)&wg_s[g * 72 + qw * 8];
        const short8 bf1 = *(const short8*)&wg_s[g * 72 + qw * 8 + 32];
        const float bgv = bg_s[g];
        const float revd[8] = {15.91549431f, 6.7115081f, 2.8302193f, 1.1934936f,
                               0.5032921f, 0.2122365f, 0.0894993f, 0.0377415f};

        for (int cl = 0; cl < 16; ++cl) {
            float4 mb = *(const float4*)&mbox[cl * 16 + g][0];   // cx, cy, lw, lh
            const float p0 = (f0 == 0)
                     ? __logf(fmaxf(fabsf((cxn - mb.x) * iwn), 1e-3f))
                     : __logf(fmaxf(fabsf((cyn - mb.y) * ihn), 1e-3f));
            const float p1 = (f0 == 0) ? (lwn - mb.z) : (lhn - mb.w);
            float s0v[8], s1v[8];
#pragma unroll
            for (int rr = 0; rr < 8; ++rr) {
                const float rv = revd[rr];
                s0v[rr] = sin_rev(fmaf(p0, rv, cr));
                s1v[rr] = sin_rev(fmaf(p1, rv, cr));
            }
            union { uint4 u; short8 s; } a0, a1;
            a0.u.x = cvtpk(s0v[0], s0v[1]); a0.u.y = cvtpk(s0v[2], s0v[3]);
            a0.u.z = cvtpk(s0v[4], s0v[5]); a0.u.w = cvtpk(s0v[6], s0v[7]);
            a1.u.x = cvtpk(s1v[0], s1v[1]); a1.u.y = cvtpk(s1v[2], s1v[3]);
            a1.u.z = cvtpk(s1v[4], s1v[5]); a1.u.w = cvtpk(s1v[6], s1v[7]);
            f32x4 acc = {0.f, 0.f, 0.f, 0.f};
            acc = __builtin_amdgcn_mfma_f32_16x16x32_bf16(a0.s, bf0, acc, 0, 0, 0);
            acc = __builtin_amdgcn_mfma_f32_16x16x32_bf16(a1.s, bf1, acc, 0, 0, 0);
            const float l0 = __logf(fmaxf(acc[0] + bgv, 1e-6f));
            const float l1 = __logf(fmaxf(acc[1] + bgv, 1e-6f));
            const float l2 = __logf(fmaxf(acc[2] + bgv, 1e-6f));
            const float l3 = __logf(fmaxf(acc[3] + bgv, 1e-6f));
            uint2 pk;
            pk.x = cvtpk(l0, l1);
            pk.y = cvtpk(l2, l3);
            *(uint2*)&pt[g * 140 + (cl & 7) * 16 + qw * 4] = pk;

            if ((cl & 7) == 7) {
                const int fl = cl >> 3;
                const int gg = lane >> 2, c4 = lane & 3;
                unsigned short* op = logw + (size_t)n * 16384 + gg * 1024 + mc + fl * 128;
                const unsigned short* rp = &pt[gg * 140];
#pragma unroll
                for (int j = 0; j < 8; ++j) {
                    const int mo = (c4 + j * 4) * 4;
                    *(uint2*)&op[mo] = *(const uint2*)&rp[mo];
                }
            }
        }
    }
}

// ---------------------------------------------------------------------------
// attn: r13/r18 version (flash, DMA-staged K/FW/logw double-buffered LDS,
// 4 waves, __syncthreads per chunk) — known-good.
// ---------------------------------------------------------------------------
#define QOFF 0
#define KOFF 8192
#define FOFF 24576
#define LOFF 40960
#define POFF 57344
#define PPAD 72

__global__ __launch_bounds__(256) void attn_kernel(
    const unsigned short* __restrict__ qb, const unsigned short* __restrict__ kb,
    const unsigned short* __restrict__ logw, const unsigned short* __restrict__ FWt,
    const float* __restrict__ bv, float* __restrict__ out)
{
    __shared__ __align__(16) char smem[66560];

    const int t = threadIdx.x;
    const int bid = blockIdx.x;
    const int g  = (bid & 7) * 2 + ((bid >> 3) >> 4);
    const int n0 = ((bid >> 3) & 15) * 64;

    const int lane = t & 63, W = t >> 6;
    const int qw = lane >> 4, lx = lane & 15;
    const int lx7 = lx & 7;
    const int r8 = lane >> 3, u = lane & 7;

#define GLD(srcp, ldsoff) __builtin_amdgcn_global_load_lds( \
        (const __attribute__((address_space(1))) void*)(srcp), \
        (__attribute__((address_space(3))) void*)(smem + (ldsoff)), 16, 0, 0)

#pragma unroll
    for (int j = 0; j < 2; ++j) {
        const int c = W * 2 + j;
        const int r = c * 8 + r8;
        GLD(qb + (size_t)(n0 + r) * 1024 + g * 64 + ((u ^ (r & 7)) * 8),
            QOFF + c * 1024);
        GLD(kb + (size_t)r * 1024 + g * 64 + ((u ^ (r & 7)) * 8),
            KOFF + c * 1024);
        GLD(FWt + (size_t)(g * 64 + r) * 1024 + ((u ^ (r & 7)) * 8),
            FOFF + c * 1024);
        GLD(logw + (size_t)(n0 + r) * 16384 + g * 1024 + (((2 * u) ^ (r & 6)) * 4),
            LOFF + c * 1024);
    }
    __syncthreads();

    const unsigned short* qS = (const unsigned short*)(smem + QOFF);
    const int qrow = W * 16 + lx;
    const short8 bq0 = *(const short8*)(qS + qrow * 64 + ((qw ^ lx7) * 8));
    const short8 bq1 = *(const short8*)(qS + qrow * 64 + (((qw + 4) ^ lx7) * 8));
    unsigned short* Pw = (unsigned short*)(smem + POFF) + W * 16 * PPAD;

    f32x4 acc[4];
    const f32x4 z4 = {0.f, 0.f, 0.f, 0.f};
#pragma unroll
    for (int nb = 0; nb < 4; ++nb) acc[nb] = z4;
    float mrow = -1e30f, srow = 0.f;

    for (int i = 0; i < 16; ++i) {
        const int cur = i & 1;
        if (i < 15) {
            const int mc = (i + 1) * 64;
            const int nxt = cur ^ 1;
#pragma unroll
            for (int j = 0; j < 2; ++j) {
                const int c = W * 2 + j;
                const int r = c * 8 + r8;
                GLD(kb + (size_t)(mc + r) * 1024 + g * 64 + ((u ^ (r & 7)) * 8),
                    KOFF + nxt * 8192 + c * 1024);
                GLD(FWt + (size_t)(g * 64 + r) * 1024 + mc + ((u ^ (r & 7)) * 8),
                    FOFF + nxt * 8192 + c * 1024);
                GLD(logw + (size_t)(n0 + r) * 16384 + g * 1024 + mc
                        + (((2 * u) ^ (r & 6)) * 4),
                    LOFF + nxt * 8192 + c * 1024);
            }
        }

        const unsigned short* Kc = (const unsigned short*)(smem + KOFF + cur * 8192);
        const unsigned short* Fc = (const unsigned short*)(smem + FOFF + cur * 8192);
        const unsigned short* Lc = (const unsigned short*)(smem + LOFF + cur * 8192);

        f32x4 s[4];
#pragma unroll
        for (int tt = 0; tt < 4; ++tt) {
            const unsigned short* kr = Kc + (tt * 16 + lx) * 64;
            short8 a0 = *(const short8*)(kr + ((qw ^ lx7) * 8));
            short8 a1 = *(const short8*)(kr + (((qw + 4) ^ lx7) * 8));
            f32x4 z = z4;
            z = __builtin_amdgcn_mfma_f32_16x16x32_bf16(a0, bq0, z, 0, 0, 0);
            s[tt] = __builtin_amdgcn_mfma_f32_16x16x32_bf16(a1, bq1, z, 0, 0, 0);
        }

        const unsigned short* Lr = Lc + (W * 16 + lx) * 64;
        float v[4][4];
        float cmx = -1e30f;
#pragma unroll
        for (int tt = 0; tt < 4; ++tt) {
            const int off = ((tt * 32 + qw * 8) ^ ((lx & 6) << 3)) >> 1;
            const uint2 lw = *(const uint2*)(Lr + off);
            v[tt][0] = s[tt][0] + bf2f((unsigned short)(lw.x & 0xffff));
            v[tt][1] = s[tt][1] + bf2f((unsigned short)(lw.x >> 16));
            v[tt][2] = s[tt][2] + bf2f((unsigned short)(lw.y & 0xffff));
            v[tt][3] = s[tt][3] + bf2f((unsigned short)(lw.y >> 16));
            cmx = fmaxf(cmx, fmaxf(fmaxf(v[tt][0], v[tt][1]), fmaxf(v[tt][2], v[tt][3])));
        }
        cmx = fmaxf(cmx, __shfl_xor(cmx, 16));
        cmx = fmaxf(cmx, __shfl_xor(cmx, 32));

        const float nm = fmaxf(mrow, cmx);
        const float f  = __expf(mrow - nm);
        mrow = nm;
        srow *= f;
#pragma unroll
        for (int nb = 0; nb < 4; ++nb) {
            acc[nb][0] *= f; acc[nb][1] *= f;
            acc[nb][2] *= f; acc[nb][3] *= f;
        }

#pragma unroll
        for (int tt = 0; tt < 4; ++tt) {
            const float p0 = __expf(v[tt][0] - nm);
            const float p1 = __expf(v[tt][1] - nm);
            const float p2 = __expf(v[tt][2] - nm);
            const float p3 = __expf(v[tt][3] - nm);
            srow += (p0 + p1) + (p2 + p3);
            uint2 pk;
            pk.x = cvtpk(p0, p1);
            pk.y = cvtpk(p2, p3);
            *(uint2*)&Pw[lx * PPAD + tt * 16 + qw * 4] = pk;
        }

#pragma unroll
        for (int ks = 0; ks < 2; ++ks) {
            const short8 ap = *(const short8*)&Pw[lx * PPAD + ks * 32 + qw * 8];
#pragma unroll
            for (int nb = 0; nb < 4; ++nb) {
                const unsigned short* fr = Fc + (nb * 16 + lx) * 64;
                short8 fb = *(const short8*)(fr + (((ks * 4 + qw) ^ lx7) * 8));
                acc[nb] = __builtin_amdgcn_mfma_f32_16x16x32_bf16(fb, ap, acc[nb], 0, 0, 0);
            }
        }

        __syncthreads();   // drains DMA for i+1; all waves done with cur
    }

    srow += __shfl_xor(srow, 16);
    srow += __shfl_xor(srow, 32);
    const float inv = 1.f / srow;
    float* Ow = (float*)smem + W * 16 * 68;
#pragma unroll
    for (int nb = 0; nb < 4; ++nb)
#pragma unroll
        for (int r = 0; r < 4; ++r)
            Ow[lx * 68 + nb * 16 + qw * 4 + r] = acc[nb][r] * inv;
    {
        const int row = lane >> 2, d0 = (lane & 3) * 16;
        const float* Orow = (float*)smem + W * 16 * 68 + row * 68;
        float* op = out + (size_t)(n0 + W * 16 + row) * 1024 + g * 64 + d0;
#pragma unroll
        for (int j = 0; j < 4; ++j) {
            float4 o = *(const float4*)(Orow + d0 + j * 4);
            const float4 b4 = *(const float4*)&bv[g * 64 + d0 + j * 4];
            o.x += b4.x; o.y += b4.y; o.z += b4.z; o.w += b4.w;
            *(float4*)(op + j * 4) = o;
        }
    }
#undef GLD
}

extern "C" void kernel_launch(void* const* d_in, const int* in_sizes, int n_in,
                              void* d_out, int out_size, void* d_ws, size_t ws_size,
                              hipStream_t stream)
{
    const float* feats = (const float*)d_in[0];
    const float* rois  = (const float*)d_in[1];
    const float* Wq    = (const float*)d_in[2];
    const float* bq    = (const float*)d_in[3];
    const float* Wk    = (const float*)d_in[4];
    const float* bk    = (const float*)d_in[5];
    const float* Wg    = (const float*)d_in[6];
    const float* bg    = (const float*)d_in[7];
    const float* Wv    = (const float*)d_in[8];
    const float* bv    = (const float*)d_in[9];
    float* out = (float*)d_out;

    char* wsb = (char*)d_ws;
    unsigned short* logwb  = (unsigned short*)(wsb + (0ull  << 20));  // 32MB
    unsigned short* featsb = (unsigned short*)(wsb + (64ull << 20));
    unsigned short* qb     = (unsigned short*)(wsb + (66ull << 20));
    unsigned short* kb     = (unsigned short*)(wsb + (68ull << 20));
    unsigned short* FWtb   = (unsigned short*)(wsb + (70ull << 20));
    unsigned short* Wqb    = (unsigned short*)(wsb + (80ull << 20));  // away from logw
    unsigned short* Wkb    = (unsigned short*)(wsb + (82ull << 20));
    unsigned short* Wvb    = (unsigned short*)(wsb + (84ull << 20));

    cvt_kernel<<<dim3(512, 4), 256, 0, stream>>>(feats, Wq, Wk, Wv,
                                                 featsb, Wqb, Wkb, Wvb);

    Triples tr;
    tr.A[0] = featsb; tr.B[0] = Wqb;    tr.C[0] = qb;   tr.bias[0] = bq;
    tr.A[1] = featsb; tr.B[1] = Wkb;    tr.C[1] = kb;   tr.bias[1] = bk;
    tr.A[2] = Wvb;    tr.B[2] = featsb; tr.C[2] = FWtb; tr.bias[2] = nullptr;
    prep_kernel<<<1408, 256, 0, stream>>>(tr, rois, Wg, bg, logwb);

    attn_kernel<<<256, 256, 0, stream>>>(qb, kb, logwb, FWtb, bv, out);
}